// Round 11
// baseline (172.653 us; speedup 1.0000x reference)
//
#include <hip/hip_runtime.h>
#include <math.h>

#define NHEAD 8
#define SROW 1088          // kh/kl row count per head
#define PSTR 1088          // compact p row stride (bf16)
#define VSTR 1056          // vT row length (bf16)
#define LOGK 2.0794415416798357f

typedef __bf16 bf16x8 __attribute__((ext_vector_type(8)));
typedef __bf16 bf16x4 __attribute__((ext_vector_type(4)));
typedef float  f32x4  __attribute__((ext_vector_type(4)));

__device__ __forceinline__ void split2(float v, __bf16& hi, __bf16& lo) {
    hi = (__bf16)v; lo = (__bf16)(v - (float)hi);
}

// ---------------- DPP wave reductions (64 lanes), result broadcast ----------------
__device__ __forceinline__ float dpp_sum64(float x) {
    int v;
    v = __builtin_amdgcn_update_dpp(0, __float_as_int(x), 0x111, 0xf, 0xf, true); x += __int_as_float(v);
    v = __builtin_amdgcn_update_dpp(0, __float_as_int(x), 0x112, 0xf, 0xf, true); x += __int_as_float(v);
    v = __builtin_amdgcn_update_dpp(0, __float_as_int(x), 0x114, 0xf, 0xf, true); x += __int_as_float(v);
    v = __builtin_amdgcn_update_dpp(0, __float_as_int(x), 0x118, 0xf, 0xf, true); x += __int_as_float(v);
    v = __builtin_amdgcn_update_dpp(0, __float_as_int(x), 0x142, 0xa, 0xf, true); x += __int_as_float(v);
    v = __builtin_amdgcn_update_dpp(0, __float_as_int(x), 0x143, 0xc, 0xf, true); x += __int_as_float(v);
    return __int_as_float(__builtin_amdgcn_readlane(__float_as_int(x), 63));
}
__device__ __forceinline__ float dpp_max64(float x) {
    int v;
    v = __builtin_amdgcn_update_dpp(__float_as_int(x), __float_as_int(x), 0x111, 0xf, 0xf, false); x = fmaxf(x, __int_as_float(v));
    v = __builtin_amdgcn_update_dpp(__float_as_int(x), __float_as_int(x), 0x112, 0xf, 0xf, false); x = fmaxf(x, __int_as_float(v));
    v = __builtin_amdgcn_update_dpp(__float_as_int(x), __float_as_int(x), 0x114, 0xf, 0xf, false); x = fmaxf(x, __int_as_float(v));
    v = __builtin_amdgcn_update_dpp(__float_as_int(x), __float_as_int(x), 0x118, 0xf, 0xf, false); x = fmaxf(x, __int_as_float(v));
    v = __builtin_amdgcn_update_dpp(__float_as_int(x), __float_as_int(x), 0x142, 0xa, 0xf, false); x = fmaxf(x, __int_as_float(v));
    v = __builtin_amdgcn_update_dpp(__float_as_int(x), __float_as_int(x), 0x143, 0xc, 0xf, false); x = fmaxf(x, __int_as_float(v));
    return __int_as_float(__builtin_amdgcn_readlane(__float_as_int(x), 63));
}

// ================== fused prep: ln (512 blk) + wsplit_qkv (192) + wsplit_out (64) + nullkv (4) ==================
__global__ __launch_bounds__(256) void prep_kernel(const float* __restrict__ x,
                                                   const float* __restrict__ g,
                                                   const float* __restrict__ bb,
                                                   const float* __restrict__ w_qkv,
                                                   const float* __restrict__ w_out,
                                                   const float* __restrict__ nkv,
                                                   __bf16* __restrict__ xnh,
                                                   __bf16* __restrict__ xnl,
                                                   __bf16* __restrict__ wqh,
                                                   __bf16* __restrict__ wql,
                                                   __bf16* __restrict__ wo,
                                                   __bf16* __restrict__ kh,
                                                   __bf16* __restrict__ kl,
                                                   __bf16* __restrict__ vT) {
    __shared__ float T[64][65];
    __shared__ float sm[2][4];
    int b = blockIdx.x, tid = threadIdx.x;

    if (b < 512) {
        int half = tid >> 7, t = tid & 127;
        int row = (b << 1) + half;
        float4 v = ((const float4*)(x + (size_t)row * 512))[t];
        float s  = v.x + v.y + v.z + v.w;
        float ss = fmaf(v.x, v.x, fmaf(v.y, v.y, fmaf(v.z, v.z, v.w * v.w)));
#pragma unroll
        for (int off = 32; off; off >>= 1) {
            s  += __shfl_down(s, off);
            ss += __shfl_down(ss, off);
        }
        int wih = (tid >> 6) & 1;
        if ((tid & 63) == 0) { sm[half][wih * 2] = s; sm[half][wih * 2 + 1] = ss; }
        __syncthreads();
        s = sm[half][0] + sm[half][2]; ss = sm[half][1] + sm[half][3];
        float mu   = s * (1.f / 512);
        float var  = ss * (1.f / 512) - mu * mu;
        float rstd = 1.f / sqrtf(var + 1e-5f);
        float4 gv = ((const float4*)g)[t];
        float4 bv = ((const float4*)bb)[t];
        float o[4];
        o[0] = (v.x - mu) * rstd * gv.x + bv.x;
        o[1] = (v.y - mu) * rstd * gv.y + bv.y;
        o[2] = (v.z - mu) * rstd * gv.z + bv.z;
        o[3] = (v.w - mu) * rstd * gv.w + bv.w;
        bf16x4 h4, l4;
#pragma unroll
        for (int e = 0; e < 4; ++e) { __bf16 hi, lo; split2(o[e], hi, lo); h4[e] = hi; l4[e] = lo; }
        *(bf16x4*)(xnh + (size_t)row * 512 + t * 4) = h4;
        *(bf16x4*)(xnl + (size_t)row * 512 + t * 4) = l4;
    } else if (b < 704) {
        int b2 = b - 512;
        int k0 = (b2 & 7) * 64, n0 = (b2 >> 3) * 64;
        int r = tid >> 2, c0 = (tid & 3) << 4;
#pragma unroll
        for (int u = 0; u < 4; ++u) {
            float4 w = *(const float4*)(w_qkv + (size_t)(k0 + r) * 1536 + n0 + c0 + 4 * u);
            T[r][c0 + 4 * u + 0] = w.x; T[r][c0 + 4 * u + 1] = w.y;
            T[r][c0 + 4 * u + 2] = w.z; T[r][c0 + 4 * u + 3] = w.w;
        }
        __syncthreads();
        int nr = tid >> 2, kc0 = (tid & 3) << 4;
#pragma unroll
        for (int u = 0; u < 4; ++u) {
            bf16x4 h4, l4;
#pragma unroll
            for (int e = 0; e < 4; ++e) {
                __bf16 hi, lo; split2(T[kc0 + 4 * u + e][nr], hi, lo);
                h4[e] = hi; l4[e] = lo;
            }
            *(bf16x4*)(wqh + (size_t)(n0 + nr) * 512 + k0 + kc0 + 4 * u) = h4;
            *(bf16x4*)(wql + (size_t)(n0 + nr) * 512 + k0 + kc0 + 4 * u) = l4;
        }
    } else if (b < 768) {
        int b2 = b - 704;
        int k0 = (b2 & 7) * 64, n0 = (b2 >> 3) * 64;
        int r = tid >> 2, c0 = (tid & 3) << 4;
#pragma unroll
        for (int u = 0; u < 4; ++u) {
            float4 w = *(const float4*)(w_out + (size_t)(k0 + r) * 512 + n0 + c0 + 4 * u);
            T[r][c0 + 4 * u + 0] = w.x; T[r][c0 + 4 * u + 1] = w.y;
            T[r][c0 + 4 * u + 2] = w.z; T[r][c0 + 4 * u + 3] = w.w;
        }
        __syncthreads();
        int nr = tid >> 2, kc0 = (tid & 3) << 4;
#pragma unroll
        for (int u = 0; u < 4; ++u) {
            bf16x4 h4;
#pragma unroll
            for (int e = 0; e < 4; ++e) h4[e] = (__bf16)T[kc0 + 4 * u + e][nr];
            *(bf16x4*)(wo + (size_t)(n0 + nr) * 512 + k0 + kc0 + 4 * u) = h4;
        }
    } else {
        int t2 = (b - 768) * 256 + tid;   // 0..1023
        int d = t2 & 63, p = (t2 >> 6) & 1, h = t2 >> 7;
        float kvf = nkv[((0 * NHEAD + h) * 2 + p) * 64 + d];
        __bf16 hi, lo; split2(kvf, hi, lo);
        kh[((size_t)h * SROW + p) * 64 + d] = hi;
        kl[((size_t)h * SROW + p) * 64 + d] = lo;
        float vf = nkv[((NHEAD + h) * 2 + p) * 64 + d];
        vT[((size_t)(h * 64) + d) * VSTR + p] = (__bf16)vf;
        int base = t2 * 15;
#pragma unroll
        for (int e = 0; e < 15; ++e) {
            int z = base + e;
            int jj = 1026 + (z % 30);
            int hd = z / 30;
            vT[(size_t)hd * VSTR + jj] = (__bf16)0.f;
        }
    }
}

// ============ QKV GEMM: LDS-free 3-pass MFMA ============
__global__ __launch_bounds__(256, 4) void qkv_mfma(const __bf16* __restrict__ xh,
                                                   const __bf16* __restrict__ xl,
                                                   const __bf16* __restrict__ bh,
                                                   const __bf16* __restrict__ bl,
                                                   __bf16* __restrict__ qh,
                                                   __bf16* __restrict__ ql,
                                                   __bf16* __restrict__ kh,
                                                   __bf16* __restrict__ kl,
                                                   __bf16* __restrict__ vT) {
    int tid = threadIdx.x, l = tid & 63, w = tid >> 6;
    int m0 = blockIdx.x * 32, n0 = blockIdx.y * 64;
    int ms = (w & 1) << 4, nh2 = (w >> 1) << 5;
    int arow = m0 + ms + (l & 15);
    f32x4 acc[2] = {};
#pragma unroll 2
    for (int ks = 0; ks < 16; ++ks) {
        int koff = ((l >> 4) << 3) + (ks << 5);
        bf16x8 ah = *(const bf16x8*)(xh + (size_t)arow * 512 + koff);
        bf16x8 al = *(const bf16x8*)(xl + (size_t)arow * 512 + koff);
#pragma unroll
        for (int ct = 0; ct < 2; ++ct) {
            int ncol = n0 + nh2 + (ct << 4) + (l & 15);
            bf16x8 bhv = *(const bf16x8*)(bh + (size_t)ncol * 512 + koff);
            bf16x8 blv = *(const bf16x8*)(bl + (size_t)ncol * 512 + koff);
            acc[ct] = __builtin_amdgcn_mfma_f32_16x16x32_bf16(ah, bhv, acc[ct], 0, 0, 0);
            acc[ct] = __builtin_amdgcn_mfma_f32_16x16x32_bf16(al, bhv, acc[ct], 0, 0, 0);
            acc[ct] = __builtin_amdgcn_mfma_f32_16x16x32_bf16(ah, blv, acc[ct], 0, 0, 0);
        }
    }
#pragma unroll
    for (int ct = 0; ct < 2; ++ct) {
        int c = n0 + nh2 + (ct << 4) + (l & 15);
#pragma unroll
        for (int r = 0; r < 4; ++r) {
            int m = m0 + ms + ((l >> 4) << 2) + r;
            float val = acc[ct][r];
            if (c < 512) {
                int h = c >> 6, d = c & 63;
                __bf16 hi, lo; split2(val * 1.25f, hi, lo);   // 0.125 scale * 10 (1/eps)
                qh[(((size_t)(h << 10)) + m) * 64 + d] = hi;
                ql[(((size_t)(h << 10)) + m) * 64 + d] = lo;
            } else if (c < 1024) {
                int c2 = c - 512, h = c2 >> 6, d = c2 & 63;
                __bf16 hi, lo; split2(val, hi, lo);
                kh[((size_t)h * SROW + 2 + m) * 64 + d] = hi;
                kl[((size_t)h * SROW + 2 + m) * 64 + d] = lo;
            } else {
                int c2 = c - 1024, h = c2 >> 6, d = c2 & 63;
                vT[((size_t)(h * 64) + d) * VSTR + 2 + m] = (__bf16)val;
            }
        }
    }
}

// ============ FUSED QK^T + CD: block = 8 pairs (16 rows) of one head ============
// Swapped MFMA: A = K-tile (j x k), B = Q rows ([row][k] read as [k][col]) ->
// D row = j, col = q-row. s staged in LDS; CD per wave from LDS; p -> compact pbuf.
__global__ __launch_bounds__(512, 4) void qkcd_kernel(const __bf16* __restrict__ qh,
                                                      const __bf16* __restrict__ ql,
                                                      const __bf16* __restrict__ kh,
                                                      const __bf16* __restrict__ kl,
                                                      __bf16* __restrict__ pbuf) {
    __shared__ float s_lds[1040 * 17];   // [j][16 rows + 1 pad]
    int tid = threadIdx.x, l = tid & 63, w = tid >> 6;
    int ip0 = blockIdx.x << 3, h = blockIdx.y;
    int ext = 1026 - ip0;
    int T = (ext + 15) >> 4;             // 16-j tiles to compute

    int c16 = l & 15;
    int kgrp = (l >> 4) << 3;
    // B fragments: 16 q rows = 8 A-rows (cols 0..7) + 8 B-rows (cols 8..15)
    int row16 = (c16 < 8) ? (1016 - ip0 + c16) : (ip0 + c16 - 8);
    const __bf16* qrb = qh + ((size_t)(h << 10) + row16) * 64 + kgrp;
    const __bf16* qrl = ql + ((size_t)(h << 10) + row16) * 64 + kgrp;
    bf16x8 qB0 = *(const bf16x8*)(qrb);
    bf16x8 qB1 = *(const bf16x8*)(qrb + 32);
    bf16x8 qL0 = *(const bf16x8*)(qrl);
    bf16x8 qL1 = *(const bf16x8*)(qrl + 32);

    const __bf16* khb = kh + ((size_t)h * SROW) * 64;
    const __bf16* klb = kl + ((size_t)h * SROW) * 64;
    for (int jt = w; jt < T; jt += 8) {
        int jg = (jt << 4) + c16;
        const __bf16* ka = khb + (size_t)jg * 64 + kgrp;
        const __bf16* kb = klb + (size_t)jg * 64 + kgrp;
        f32x4 acc = {};
        bf16x8 ah0 = *(const bf16x8*)(ka);
        bf16x8 al0 = *(const bf16x8*)(kb);
        bf16x8 ah1 = *(const bf16x8*)(ka + 32);
        bf16x8 al1 = *(const bf16x8*)(kb + 32);
        acc = __builtin_amdgcn_mfma_f32_16x16x32_bf16(ah0, qB0, acc, 0, 0, 0);
        acc = __builtin_amdgcn_mfma_f32_16x16x32_bf16(al0, qB0, acc, 0, 0, 0);
        acc = __builtin_amdgcn_mfma_f32_16x16x32_bf16(ah0, qL0, acc, 0, 0, 0);
        acc = __builtin_amdgcn_mfma_f32_16x16x32_bf16(ah1, qB1, acc, 0, 0, 0);
        acc = __builtin_amdgcn_mfma_f32_16x16x32_bf16(al1, qB1, acc, 0, 0, 0);
        acc = __builtin_amdgcn_mfma_f32_16x16x32_bf16(ah1, qL1, acc, 0, 0, 0);
        int jb0 = (jt << 4) + ((l >> 4) << 2);
#pragma unroll
        for (int r = 0; r < 4; ++r)
            s_lds[(jb0 + r) * 17 + c16] = acc[r];
    }
    __syncthreads();

    // ---- CD: wave w owns pair ip = ip0 + w ----
    int ip = ip0 + w;
    int iA = 1023 - ip, iB = ip;
    int nvA = iA + 3, nvB = iB + 3;
    int colA = 7 - w, colB = 8 + w;
    int jb = l << 2;

    float4 EA[5], EB[3];
    float mA = -INFINITY, mB = -INFINITY;
#pragma unroll
    for (int t = 0; t < 5; ++t) {
        float* sp = (float*)&EA[t];
#pragma unroll
        for (int c = 0; c < 4; ++c) {
            int j = jb + c + (t << 8);
            float v = (j < nvA) ? s_lds[j * 17 + colA] : -INFINITY;
            sp[c] = v; mA = fmaxf(mA, v);
        }
    }
#pragma unroll
    for (int t = 0; t < 3; ++t) {
        float* sp = (float*)&EB[t];
#pragma unroll
        for (int c = 0; c < 4; ++c) {
            int j = jb + c + (t << 8);
            float v = (j < nvB) ? s_lds[j * 17 + colB] : -INFINITY;
            sp[c] = v; mB = fmaxf(mB, v);
        }
    }
    mA = dpp_max64(mA); mB = dpp_max64(mB);

#pragma unroll
    for (int t = 0; t < 5; ++t) {
        float* sp = (float*)&EA[t];
#pragma unroll
        for (int c = 0; c < 4; ++c) sp[c] = __expf(sp[c] - mA);
    }
#pragma unroll
    for (int t = 0; t < 3; ++t) {
        float* sp = (float*)&EB[t];
#pragma unroll
        for (int c = 0; c < 4; ++c) sp[c] = __expf(sp[c] - mB);
    }

    float gA = LOGK - __logf((float)nvA) + mA;
    float gB = LOGK - __logf((float)nvB) + mB;
    bool dA = false, dB = false;
#pragma unroll 1
    for (int it = 1; it < 50; ++it) {
        if (!dA) {
            float eg = __expf(fminf(gA, 80.f));
            float a0 = 0.f, a1 = 0.f, a2 = 0.f, a3 = 0.f;
#pragma unroll
            for (int t = 0; t < 5; ++t) {
                float* ep = (float*)&EA[t];
                a0 += ep[0] * fminf(1.f, ep[0] * eg);
                a1 += ep[1] * fminf(1.f, ep[1] * eg);
                a2 += ep[2] * fminf(1.f, ep[2] * eg);
                a3 += ep[3] * fminf(1.f, ep[3] * eg);
            }
            float sum = dpp_sum64((a0 + a1) + (a2 + a3));
            float g2 = LOGK - __logf(sum);
            dA = (__float_as_int(g2) == __float_as_int(gA));
            gA = g2;
        }
        if (!dB) {
            float eg = __expf(fminf(gB, 80.f));
            float b0 = 0.f, b1 = 0.f, b2 = 0.f, b3 = 0.f;
#pragma unroll
            for (int t = 0; t < 3; ++t) {
                float* ep = (float*)&EB[t];
                b0 += ep[0] * fminf(1.f, ep[0] * eg);
                b1 += ep[1] * fminf(1.f, ep[1] * eg);
                b2 += ep[2] * fminf(1.f, ep[2] * eg);
                b3 += ep[3] * fminf(1.f, ep[3] * eg);
            }
            float sum = dpp_sum64((b0 + b1) + (b2 + b3));
            float g2 = LOGK - __logf(sum);
            dB = (__float_as_int(g2) == __float_as_int(gB));
            gB = g2;
        }
        if (dA && dB) break;
    }

    // ---- final p -> compact pbuf rows (zeros beyond nv) ----
    float egA = __expf(fminf(gA, 80.f));
    float egB = __expf(fminf(gB, 80.f));
    __bf16* pA = pbuf + ((size_t)(h << 10) + iA) * PSTR;
    __bf16* pB = pbuf + ((size_t)(h << 10) + iB) * PSTR;
#pragma unroll
    for (int t = 0; t < 5; ++t) {
        if (jb + (t << 8) < PSTR) {
            bf16x4 pv;
            float* ep = (float*)&EA[t];
#pragma unroll
            for (int c = 0; c < 4; ++c) {
                float wv = ep[c] * egA;
                pv[c] = (__bf16)(wv * fminf(1.f, wv));
            }
            *(bf16x4*)(pA + jb + (t << 8)) = pv;
        }
    }
#pragma unroll
    for (int t = 0; t < 3; ++t) {
        bf16x4 pv;
        float* ep = (float*)&EB[t];
#pragma unroll
        for (int c = 0; c < 4; ++c) {
            float wv = ep[c] * egB;
            pv[c] = (__bf16)(wv * fminf(1.f, wv));
        }
        *(bf16x4*)(pB + jb + (t << 8)) = pv;
    }
    bf16x4 z4 = {};
#pragma unroll
    for (int t = 3; t < 5; ++t) {
        if (jb + (t << 8) < PSTR) *(bf16x4*)(pB + jb + (t << 8)) = z4;
    }
}

// ============ PV: LDS-free bf16 MFMA. grid (64, 8): tile 16i x 64d ============
__global__ __launch_bounds__(256, 4) void pv_mfma(const __bf16* __restrict__ pbuf,
                                                  const __bf16* __restrict__ vT,
                                                  __bf16* __restrict__ ao) {
    int i0 = blockIdx.x << 4, h = blockIdx.y;
    int tid = threadIdx.x, l = tid & 63, w = tid >> 6;
    int arow = i0 + (l & 15);
    int dcol = (w << 4) + (l & 15);
    const __bf16* pr = pbuf + ((size_t)(h << 10) + arow) * PSTR;
    const __bf16* vr = vT + ((size_t)(h << 6) + dcol) * VSTR;
    f32x4 acc0 = {}, acc1 = {};
    int kb = (l >> 4) << 3;
#pragma unroll 4
    for (int ks = 0; ks < 32; ks += 2) {
        bf16x8 a0 = *(const bf16x8*)(pr + kb + (ks << 5));
        bf16x8 b0 = *(const bf16x8*)(vr + kb + (ks << 5));
        bf16x8 a1 = *(const bf16x8*)(pr + kb + ((ks + 1) << 5));
        bf16x8 b1 = *(const bf16x8*)(vr + kb + ((ks + 1) << 5));
        acc0 = __builtin_amdgcn_mfma_f32_16x16x32_bf16(a0, b0, acc0, 0, 0, 0);
        acc1 = __builtin_amdgcn_mfma_f32_16x16x32_bf16(a1, b1, acc1, 0, 0, 0);
    }
    {
        bf16x8 a0 = *(const bf16x8*)(pr + kb + (32 << 5));
        bf16x8 b0 = *(const bf16x8*)(vr + kb + (32 << 5));
        acc0 = __builtin_amdgcn_mfma_f32_16x16x32_bf16(a0, b0, acc0, 0, 0, 0);
    }
#pragma unroll
    for (int r = 0; r < 4; ++r) {
        int i = i0 + ((l >> 4) << 2) + r;
        ao[(size_t)i * 512 + (h << 6) + dcol] = (__bf16)(acc0[r] + acc1[r]);
    }
}

// ============ OUT: LDS-free bf16 MFMA. grid (64, 8): tile 16m x 64n ============
__global__ __launch_bounds__(256, 4) void out_mfma(const __bf16* __restrict__ ao,
                                                   const __bf16* __restrict__ wo,
                                                   float* __restrict__ out) {
    int m0 = blockIdx.x << 4, bn = blockIdx.y;
    int tid = threadIdx.x, l = tid & 63, w = tid >> 6;
    int arow = m0 + (l & 15);
    int ncol = (bn << 6) + (w << 4) + (l & 15);
    const __bf16* ar = ao + (size_t)arow * 512;
    const __bf16* br = wo + (size_t)ncol * 512;
    f32x4 acc0 = {}, acc1 = {};
    int kb = (l >> 4) << 3;
#pragma unroll 4
    for (int ks = 0; ks < 16; ks += 2) {
        bf16x8 a0 = *(const bf16x8*)(ar + kb + (ks << 5));
        bf16x8 b0 = *(const bf16x8*)(br + kb + (ks << 5));
        bf16x8 a1 = *(const bf16x8*)(ar + kb + ((ks + 1) << 5));
        bf16x8 b1 = *(const bf16x8*)(br + kb + ((ks + 1) << 5));
        acc0 = __builtin_amdgcn_mfma_f32_16x16x32_bf16(a0, b0, acc0, 0, 0, 0);
        acc1 = __builtin_amdgcn_mfma_f32_16x16x32_bf16(a1, b1, acc1, 0, 0, 0);
    }
#pragma unroll
    for (int r = 0; r < 4; ++r) {
        int m = m0 + ((l >> 4) << 2) + r;
        out[(size_t)m * 512 + ncol] = acc0[r] + acc1[r];
    }
}

extern "C" void kernel_launch(void* const* d_in, const int* in_sizes, int n_in,
                              void* d_out, int out_size, void* d_ws, size_t ws_size,
                              hipStream_t stream) {
    const float* x      = (const float*)d_in[0];
    const float* w_qkv  = (const float*)d_in[1];
    const float* w_out  = (const float*)d_in[2];
    const float* nullkv = (const float*)d_in[3];
    const float* ln_g   = (const float*)d_in[4];
    const float* ln_b   = (const float*)d_in[5];
    float* ws = (float*)d_ws;
    float* out = (float*)d_out;

    float* base = ws;
    __bf16* xnh = (__bf16*)(base);              base += 262144;   // 1024*512 bf16
    __bf16* xnl = (__bf16*)(base);              base += 262144;
    __bf16* wqh = (__bf16*)(base);              base += 393216;   // 1536*512 bf16
    __bf16* wql = (__bf16*)(base);              base += 393216;
    __bf16* qh  = (__bf16*)(base);              base += 262144;   // 8*1024*64
    __bf16* ql  = (__bf16*)(base);              base += 262144;
    __bf16* kh  = (__bf16*)(base);              base += 278528;   // 8*1088*64
    __bf16* kl  = (__bf16*)(base);              base += 278528;
    __bf16* vT  = (__bf16*)(base);              base += 270336;   // 8*64*1056
    __bf16* wo  = (__bf16*)(base);              base += 131072;   // 512*512
    __bf16* ao  = (__bf16*)(base);              base += 262144;   // 1024*512
    __bf16* pbuf = (__bf16*)(base);                               // 8*1024*1088 bf16

    hipLaunchKernelGGL(prep_kernel, dim3(772),    dim3(256), 0, stream,
                       x, ln_g, ln_b, w_qkv, w_out, nullkv,
                       xnh, xnl, wqh, wql, wo, kh, kl, vT);
    hipLaunchKernelGGL(qkv_mfma,   dim3(32, 24),  dim3(256), 0, stream, xnh, xnl, wqh, wql, qh, ql, kh, kl, vT);
    hipLaunchKernelGGL(qkcd_kernel, dim3(64, 8),  dim3(512), 0, stream, qh, ql, kh, kl, pbuf);
    hipLaunchKernelGGL(pv_mfma,    dim3(64, 8),   dim3(256), 0, stream, pbuf, vT, ao);
    hipLaunchKernelGGL(out_mfma,   dim3(64, 8),   dim3(256), 0, stream, ao, wo, out);
}

// Round 12
// 157.931 us; speedup vs baseline: 1.0932x; 1.0932x over previous
//
#include <hip/hip_runtime.h>
#include <math.h>

#define NHEAD 8
#define SROW 1088          // kh/kl row count per head
#define VSTR 1056          // vT row length (bf16)
#define PLDS 1064          // p row stride in LDS (bf16, padded)
#define LOGK 2.0794415416798357f

typedef __bf16 bf16x8 __attribute__((ext_vector_type(8)));
typedef __bf16 bf16x4 __attribute__((ext_vector_type(4)));
typedef float  f32x4  __attribute__((ext_vector_type(4)));

__device__ __forceinline__ void split2(float v, __bf16& hi, __bf16& lo) {
    hi = (__bf16)v; lo = (__bf16)(v - (float)hi);
}

// ---------------- DPP wave reductions (64 lanes), result broadcast ----------------
__device__ __forceinline__ float dpp_sum64(float x) {
    int v;
    v = __builtin_amdgcn_update_dpp(0, __float_as_int(x), 0x111, 0xf, 0xf, true); x += __int_as_float(v);
    v = __builtin_amdgcn_update_dpp(0, __float_as_int(x), 0x112, 0xf, 0xf, true); x += __int_as_float(v);
    v = __builtin_amdgcn_update_dpp(0, __float_as_int(x), 0x114, 0xf, 0xf, true); x += __int_as_float(v);
    v = __builtin_amdgcn_update_dpp(0, __float_as_int(x), 0x118, 0xf, 0xf, true); x += __int_as_float(v);
    v = __builtin_amdgcn_update_dpp(0, __float_as_int(x), 0x142, 0xa, 0xf, true); x += __int_as_float(v);
    v = __builtin_amdgcn_update_dpp(0, __float_as_int(x), 0x143, 0xc, 0xf, true); x += __int_as_float(v);
    return __int_as_float(__builtin_amdgcn_readlane(__float_as_int(x), 63));
}
__device__ __forceinline__ float dpp_max64(float x) {
    int v;
    v = __builtin_amdgcn_update_dpp(__float_as_int(x), __float_as_int(x), 0x111, 0xf, 0xf, false); x = fmaxf(x, __int_as_float(v));
    v = __builtin_amdgcn_update_dpp(__float_as_int(x), __float_as_int(x), 0x112, 0xf, 0xf, false); x = fmaxf(x, __int_as_float(v));
    v = __builtin_amdgcn_update_dpp(__float_as_int(x), __float_as_int(x), 0x114, 0xf, 0xf, false); x = fmaxf(x, __int_as_float(v));
    v = __builtin_amdgcn_update_dpp(__float_as_int(x), __float_as_int(x), 0x118, 0xf, 0xf, false); x = fmaxf(x, __int_as_float(v));
    v = __builtin_amdgcn_update_dpp(__float_as_int(x), __float_as_int(x), 0x142, 0xa, 0xf, false); x = fmaxf(x, __int_as_float(v));
    v = __builtin_amdgcn_update_dpp(__float_as_int(x), __float_as_int(x), 0x143, 0xc, 0xf, false); x = fmaxf(x, __int_as_float(v));
    return __int_as_float(__builtin_amdgcn_readlane(__float_as_int(x), 63));
}

// ================== fused prep ==================
__global__ __launch_bounds__(256) void prep_kernel(const float* __restrict__ x,
                                                   const float* __restrict__ g,
                                                   const float* __restrict__ bb,
                                                   const float* __restrict__ w_qkv,
                                                   const float* __restrict__ w_out,
                                                   const float* __restrict__ nkv,
                                                   __bf16* __restrict__ xnh,
                                                   __bf16* __restrict__ xnl,
                                                   __bf16* __restrict__ wqh,
                                                   __bf16* __restrict__ wql,
                                                   __bf16* __restrict__ wo,
                                                   __bf16* __restrict__ kh,
                                                   __bf16* __restrict__ kl,
                                                   __bf16* __restrict__ vT) {
    __shared__ float T[64][65];
    __shared__ float sm[2][4];
    int b = blockIdx.x, tid = threadIdx.x;

    if (b < 512) {
        int half = tid >> 7, t = tid & 127;
        int row = (b << 1) + half;
        float4 v = ((const float4*)(x + (size_t)row * 512))[t];
        float s  = v.x + v.y + v.z + v.w;
        float ss = fmaf(v.x, v.x, fmaf(v.y, v.y, fmaf(v.z, v.z, v.w * v.w)));
#pragma unroll
        for (int off = 32; off; off >>= 1) {
            s  += __shfl_down(s, off);
            ss += __shfl_down(ss, off);
        }
        int wih = (tid >> 6) & 1;
        if ((tid & 63) == 0) { sm[half][wih * 2] = s; sm[half][wih * 2 + 1] = ss; }
        __syncthreads();
        s = sm[half][0] + sm[half][2]; ss = sm[half][1] + sm[half][3];
        float mu   = s * (1.f / 512);
        float var  = ss * (1.f / 512) - mu * mu;
        float rstd = 1.f / sqrtf(var + 1e-5f);
        float4 gv = ((const float4*)g)[t];
        float4 bv = ((const float4*)bb)[t];
        float o[4];
        o[0] = (v.x - mu) * rstd * gv.x + bv.x;
        o[1] = (v.y - mu) * rstd * gv.y + bv.y;
        o[2] = (v.z - mu) * rstd * gv.z + bv.z;
        o[3] = (v.w - mu) * rstd * gv.w + bv.w;
        bf16x4 h4, l4;
#pragma unroll
        for (int e = 0; e < 4; ++e) { __bf16 hi, lo; split2(o[e], hi, lo); h4[e] = hi; l4[e] = lo; }
        *(bf16x4*)(xnh + (size_t)row * 512 + t * 4) = h4;
        *(bf16x4*)(xnl + (size_t)row * 512 + t * 4) = l4;
    } else if (b < 704) {
        int b2 = b - 512;
        int k0 = (b2 & 7) * 64, n0 = (b2 >> 3) * 64;
        int r = tid >> 2, c0 = (tid & 3) << 4;
#pragma unroll
        for (int u = 0; u < 4; ++u) {
            float4 w = *(const float4*)(w_qkv + (size_t)(k0 + r) * 1536 + n0 + c0 + 4 * u);
            T[r][c0 + 4 * u + 0] = w.x; T[r][c0 + 4 * u + 1] = w.y;
            T[r][c0 + 4 * u + 2] = w.z; T[r][c0 + 4 * u + 3] = w.w;
        }
        __syncthreads();
        int nr = tid >> 2, kc0 = (tid & 3) << 4;
#pragma unroll
        for (int u = 0; u < 4; ++u) {
            bf16x4 h4, l4;
#pragma unroll
            for (int e = 0; e < 4; ++e) {
                __bf16 hi, lo; split2(T[kc0 + 4 * u + e][nr], hi, lo);
                h4[e] = hi; l4[e] = lo;
            }
            *(bf16x4*)(wqh + (size_t)(n0 + nr) * 512 + k0 + kc0 + 4 * u) = h4;
            *(bf16x4*)(wql + (size_t)(n0 + nr) * 512 + k0 + kc0 + 4 * u) = l4;
        }
    } else if (b < 768) {
        int b2 = b - 704;
        int k0 = (b2 & 7) * 64, n0 = (b2 >> 3) * 64;
        int r = tid >> 2, c0 = (tid & 3) << 4;
#pragma unroll
        for (int u = 0; u < 4; ++u) {
            float4 w = *(const float4*)(w_out + (size_t)(k0 + r) * 512 + n0 + c0 + 4 * u);
            T[r][c0 + 4 * u + 0] = w.x; T[r][c0 + 4 * u + 1] = w.y;
            T[r][c0 + 4 * u + 2] = w.z; T[r][c0 + 4 * u + 3] = w.w;
        }
        __syncthreads();
        int nr = tid >> 2, kc0 = (tid & 3) << 4;
#pragma unroll
        for (int u = 0; u < 4; ++u) {
            bf16x4 h4;
#pragma unroll
            for (int e = 0; e < 4; ++e) h4[e] = (__bf16)T[kc0 + 4 * u + e][nr];
            *(bf16x4*)(wo + (size_t)(n0 + nr) * 512 + k0 + kc0 + 4 * u) = h4;
        }
    } else {
        int t2 = (b - 768) * 256 + tid;   // 0..1023
        int d = t2 & 63, p = (t2 >> 6) & 1, h = t2 >> 7;
        float kvf = nkv[((0 * NHEAD + h) * 2 + p) * 64 + d];
        __bf16 hi, lo; split2(kvf, hi, lo);
        kh[((size_t)h * SROW + p) * 64 + d] = hi;
        kl[((size_t)h * SROW + p) * 64 + d] = lo;
        float vf = nkv[((NHEAD + h) * 2 + p) * 64 + d];
        vT[((size_t)(h * 64) + d) * VSTR + p] = (__bf16)vf;
        int base = t2 * 15;
#pragma unroll
        for (int e = 0; e < 15; ++e) {
            int z = base + e;
            int jj = 1026 + (z % 30);
            int hd = z / 30;
            vT[(size_t)hd * VSTR + jj] = (__bf16)0.f;
        }
    }
}

// ============ QKV GEMM: LDS-free 3-pass MFMA ============
__global__ __launch_bounds__(256, 4) void qkv_mfma(const __bf16* __restrict__ xh,
                                                   const __bf16* __restrict__ xl,
                                                   const __bf16* __restrict__ bh,
                                                   const __bf16* __restrict__ bl,
                                                   __bf16* __restrict__ qh,
                                                   __bf16* __restrict__ ql,
                                                   __bf16* __restrict__ kh,
                                                   __bf16* __restrict__ kl,
                                                   __bf16* __restrict__ vT) {
    int tid = threadIdx.x, l = tid & 63, w = tid >> 6;
    int m0 = blockIdx.x * 32, n0 = blockIdx.y * 64;
    int ms = (w & 1) << 4, nh2 = (w >> 1) << 5;
    int arow = m0 + ms + (l & 15);
    f32x4 acc[2] = {};
#pragma unroll 2
    for (int ks = 0; ks < 16; ++ks) {
        int koff = ((l >> 4) << 3) + (ks << 5);
        bf16x8 ah = *(const bf16x8*)(xh + (size_t)arow * 512 + koff);
        bf16x8 al = *(const bf16x8*)(xl + (size_t)arow * 512 + koff);
#pragma unroll
        for (int ct = 0; ct < 2; ++ct) {
            int ncol = n0 + nh2 + (ct << 4) + (l & 15);
            bf16x8 bhv = *(const bf16x8*)(bh + (size_t)ncol * 512 + koff);
            bf16x8 blv = *(const bf16x8*)(bl + (size_t)ncol * 512 + koff);
            acc[ct] = __builtin_amdgcn_mfma_f32_16x16x32_bf16(ah, bhv, acc[ct], 0, 0, 0);
            acc[ct] = __builtin_amdgcn_mfma_f32_16x16x32_bf16(al, bhv, acc[ct], 0, 0, 0);
            acc[ct] = __builtin_amdgcn_mfma_f32_16x16x32_bf16(ah, blv, acc[ct], 0, 0, 0);
        }
    }
#pragma unroll
    for (int ct = 0; ct < 2; ++ct) {
        int c = n0 + nh2 + (ct << 4) + (l & 15);
#pragma unroll
        for (int r = 0; r < 4; ++r) {
            int m = m0 + ms + ((l >> 4) << 2) + r;
            float val = acc[ct][r];
            if (c < 512) {
                int h = c >> 6, d = c & 63;
                __bf16 hi, lo; split2(val * 1.25f, hi, lo);   // 0.125 scale * 10 (1/eps)
                qh[(((size_t)(h << 10)) + m) * 64 + d] = hi;
                ql[(((size_t)(h << 10)) + m) * 64 + d] = lo;
            } else if (c < 1024) {
                int c2 = c - 512, h = c2 >> 6, d = c2 & 63;
                __bf16 hi, lo; split2(val, hi, lo);
                kh[((size_t)h * SROW + 2 + m) * 64 + d] = hi;
                kl[((size_t)h * SROW + 2 + m) * 64 + d] = lo;
            } else {
                int c2 = c - 1024, h = c2 >> 6, d = c2 & 63;
                vT[((size_t)(h * 64) + d) * VSTR + 2 + m] = (__bf16)val;
            }
        }
    }
}

// ============ FUSED QK^T + CD + PV: block = 8 pairs (16 rows) of one head ============
// Phase 1: swapped MFMA -> s_lds[j][16]. Phase 2: CD per wave (registers).
// Phase 3: p (bf16) -> LDS (aliases dead s_lds). Phase 4: PV MFMA -> ao.
__global__ __launch_bounds__(512, 4) void qkcdpv_kernel(const __bf16* __restrict__ qh,
                                                        const __bf16* __restrict__ ql,
                                                        const __bf16* __restrict__ kh,
                                                        const __bf16* __restrict__ kl,
                                                        const __bf16* __restrict__ vT,
                                                        __bf16* __restrict__ ao) {
    __shared__ float s_lds[1040 * 17];                 // 70720 B
    __bf16* p_lds  = (__bf16*)s_lds;                   // [16][PLDS] = 34048 B (aliased after CD)
    float*  redbuf = s_lds + 9000;                     // [4][16][17] = 4352 B (beyond p region)

    int tid = threadIdx.x, l = tid & 63, w = tid >> 6;
    int ip0 = blockIdx.x << 3, h = blockIdx.y;
    int ext = 1026 - ip0;
    int T = (ext + 15) >> 4;

    int c16 = l & 15;
    int kgrp = (l >> 4) << 3;
    int row16q = (c16 < 8) ? (1016 - ip0 + c16) : (ip0 + c16 - 8);
    const __bf16* qrb = qh + ((size_t)(h << 10) + row16q) * 64 + kgrp;
    const __bf16* qrl = ql + ((size_t)(h << 10) + row16q) * 64 + kgrp;
    bf16x8 qB0 = *(const bf16x8*)(qrb);
    bf16x8 qB1 = *(const bf16x8*)(qrb + 32);
    bf16x8 qL0 = *(const bf16x8*)(qrl);
    bf16x8 qL1 = *(const bf16x8*)(qrl + 32);

    const __bf16* khb = kh + ((size_t)h * SROW) * 64;
    const __bf16* klb = kl + ((size_t)h * SROW) * 64;
    for (int jt = w; jt < T; jt += 8) {
        int jg = (jt << 4) + c16;
        const __bf16* ka = khb + (size_t)jg * 64 + kgrp;
        const __bf16* kb = klb + (size_t)jg * 64 + kgrp;
        f32x4 acc = {};
        bf16x8 ah0 = *(const bf16x8*)(ka);
        bf16x8 al0 = *(const bf16x8*)(kb);
        bf16x8 ah1 = *(const bf16x8*)(ka + 32);
        bf16x8 al1 = *(const bf16x8*)(kb + 32);
        acc = __builtin_amdgcn_mfma_f32_16x16x32_bf16(ah0, qB0, acc, 0, 0, 0);
        acc = __builtin_amdgcn_mfma_f32_16x16x32_bf16(al0, qB0, acc, 0, 0, 0);
        acc = __builtin_amdgcn_mfma_f32_16x16x32_bf16(ah0, qL0, acc, 0, 0, 0);
        acc = __builtin_amdgcn_mfma_f32_16x16x32_bf16(ah1, qB1, acc, 0, 0, 0);
        acc = __builtin_amdgcn_mfma_f32_16x16x32_bf16(al1, qB1, acc, 0, 0, 0);
        acc = __builtin_amdgcn_mfma_f32_16x16x32_bf16(ah1, qL1, acc, 0, 0, 0);
        int jb0 = (jt << 4) + ((l >> 4) << 2);
#pragma unroll
        for (int r = 0; r < 4; ++r)
            s_lds[(jb0 + r) * 17 + c16] = acc[r];
    }
    __syncthreads();

    // ---- Phase 2: CD. wave w owns pair ip = ip0 + w ----
    int ip = ip0 + w;
    int iA = 1023 - ip, iB = ip;
    int nvA = iA + 3, nvB = iB + 3;
    int tA = (nvA + 255) >> 8, tB = (nvB + 255) >> 8;   // wave-uniform tile bounds
    int colA = 7 - w, colB = 8 + w;
    int jb = l << 2;

    float4 EA[5], EB[3];
    float mA = -INFINITY, mB = -INFINITY;
#pragma unroll
    for (int t = 0; t < 5; ++t) {
        float* sp = (float*)&EA[t];
        if (t < tA) {
#pragma unroll
            for (int c = 0; c < 4; ++c) {
                int j = jb + c + (t << 8);
                float v = (j < nvA) ? s_lds[j * 17 + colA] : -INFINITY;
                sp[c] = v; mA = fmaxf(mA, v);
            }
        } else { sp[0] = sp[1] = sp[2] = sp[3] = 0.f; }   // p=0 later; no sum contribution
    }
#pragma unroll
    for (int t = 0; t < 3; ++t) {
        float* sp = (float*)&EB[t];
        if (t < tB) {
#pragma unroll
            for (int c = 0; c < 4; ++c) {
                int j = jb + c + (t << 8);
                float v = (j < nvB) ? s_lds[j * 17 + colB] : -INFINITY;
                sp[c] = v; mB = fmaxf(mB, v);
            }
        } else { sp[0] = sp[1] = sp[2] = sp[3] = 0.f; }
    }
    mA = dpp_max64(mA); mB = dpp_max64(mB);
    __syncthreads();   // all s reads done; p_lds may be written after this

#pragma unroll
    for (int t = 0; t < 5; ++t) {
        float* sp = (float*)&EA[t];
        if (t < tA) {
#pragma unroll
            for (int c = 0; c < 4; ++c) sp[c] = __expf(sp[c] - mA);
        }
    }
#pragma unroll
    for (int t = 0; t < 3; ++t) {
        float* sp = (float*)&EB[t];
        if (t < tB) {
#pragma unroll
            for (int c = 0; c < 4; ++c) sp[c] = __expf(sp[c] - mB);
        }
    }

    float gA = LOGK - __logf((float)nvA) + mA;
    float gB = LOGK - __logf((float)nvB) + mB;
    bool dA = false, dB = false;
#pragma unroll 1
    for (int it = 1; it < 50; ++it) {
        if (!dA) {
            float eg = __expf(fminf(gA, 80.f));
            float a0 = 0.f, a1 = 0.f, a2 = 0.f, a3 = 0.f;
#pragma unroll
            for (int t = 0; t < 5; ++t) {
                if (t < tA) {
                    float* ep = (float*)&EA[t];
                    a0 += ep[0] * fminf(1.f, ep[0] * eg);
                    a1 += ep[1] * fminf(1.f, ep[1] * eg);
                    a2 += ep[2] * fminf(1.f, ep[2] * eg);
                    a3 += ep[3] * fminf(1.f, ep[3] * eg);
                }
            }
            float sum = dpp_sum64((a0 + a1) + (a2 + a3));
            float g2 = LOGK - __logf(sum);
            dA = (__float_as_int(g2) == __float_as_int(gA));
            gA = g2;
        }
        if (!dB) {
            float eg = __expf(fminf(gB, 80.f));
            float b0 = 0.f, b1 = 0.f, b2 = 0.f, b3 = 0.f;
#pragma unroll
            for (int t = 0; t < 3; ++t) {
                if (t < tB) {
                    float* ep = (float*)&EB[t];
                    b0 += ep[0] * fminf(1.f, ep[0] * eg);
                    b1 += ep[1] * fminf(1.f, ep[1] * eg);
                    b2 += ep[2] * fminf(1.f, ep[2] * eg);
                    b3 += ep[3] * fminf(1.f, ep[3] * eg);
                }
            }
            float sum = dpp_sum64((b0 + b1) + (b2 + b3));
            float g2 = LOGK - __logf(sum);
            dB = (__float_as_int(g2) == __float_as_int(gB));
            gB = g2;
        }
        if (dA && dB) break;
    }

    // ---- Phase 3: p (bf16) -> p_lds rows colA, colB (zeros through j<1056) ----
    {
        float egA = __expf(fminf(gA, 80.f));
        float egB = __expf(fminf(gB, 80.f));
        __bf16* prA = p_lds + (size_t)colA * PLDS;
        __bf16* prB = p_lds + (size_t)colB * PLDS;
#pragma unroll
        for (int t = 0; t < 5; ++t) {
            int j0 = jb + (t << 8);
            if (j0 < 1056) {
                bf16x4 pv;
                float* ep = (float*)&EA[t];
#pragma unroll
                for (int c = 0; c < 4; ++c) {
                    float wv = ep[c] * egA;
                    pv[c] = (__bf16)(wv * fminf(1.f, wv));
                }
                *(bf16x4*)(prA + j0) = pv;
            }
        }
#pragma unroll
        for (int t = 0; t < 3; ++t) {
            int j0 = jb + (t << 8);
            if (j0 < 1056) {
                bf16x4 pv;
                float* ep = (float*)&EB[t];
#pragma unroll
                for (int c = 0; c < 4; ++c) {
                    float wv = ep[c] * egB;
                    pv[c] = (__bf16)(wv * fminf(1.f, wv));
                }
                *(bf16x4*)(prB + j0) = pv;
            }
        }
        bf16x4 z4 = {};
#pragma unroll
        for (int t = 3; t < 5; ++t) {
            int j0 = jb + (t << 8);
            if (j0 < 1056) *(bf16x4*)(prB + j0) = z4;
        }
    }
    __syncthreads();

    // ---- Phase 4: PV. wave w: d-block (w&3), K-half (w>>2). 16 rows x 16 d each ----
    {
        int dblk = (w & 3) << 4;
        int dcol = dblk + c16;
        int khalf = w >> 2;
        const __bf16* vr = vT + ((size_t)(h << 6) + dcol) * VSTR;
        const __bf16* pr = p_lds + (size_t)c16 * PLDS;   // A row = lane&15
        f32x4 acc = {};
        int ks0 = khalf ? 16 : 0;
        int ks1 = khalf ? 33 : 16;
        for (int ks = ks0; ks < ks1; ++ks) {
            bf16x8 a = *(const bf16x8*)(pr + kgrp + (ks << 5));
            bf16x8 b = *(const bf16x8*)(vr + kgrp + (ks << 5));
            acc = __builtin_amdgcn_mfma_f32_16x16x32_bf16(a, b, acc, 0, 0, 0);
        }
        if (w >= 4) {
#pragma unroll
            for (int r = 0; r < 4; ++r)
                redbuf[(size_t)(w & 3) * 272 + ((l >> 4) * 4 + r) * 17 + c16] = acc[r];
        }
        __syncthreads();
        if (w < 4) {
#pragma unroll
            for (int r = 0; r < 4; ++r) {
                int row16 = (l >> 4) * 4 + r;
                float v = acc[r] + redbuf[(size_t)w * 272 + row16 * 17 + c16];
                int gi = (row16 < 8) ? (1016 - ip0 + row16) : (ip0 + row16 - 8);
                ao[(size_t)gi * 512 + (h << 6) + dcol] = (__bf16)v;
            }
        }
    }
}

// ============ OUT: LDS-free bf16 MFMA. grid (64, 8): tile 16m x 64n ============
__global__ __launch_bounds__(256, 4) void out_mfma(const __bf16* __restrict__ ao,
                                                   const __bf16* __restrict__ wo,
                                                   float* __restrict__ out) {
    int m0 = blockIdx.x << 4, bn = blockIdx.y;
    int tid = threadIdx.x, l = tid & 63, w = tid >> 6;
    int arow = m0 + (l & 15);
    int ncol = (bn << 6) + (w << 4) + (l & 15);
    const __bf16* ar = ao + (size_t)arow * 512;
    const __bf16* br = wo + (size_t)ncol * 512;
    f32x4 acc0 = {}, acc1 = {};
    int kb = (l >> 4) << 3;
#pragma unroll 4
    for (int ks = 0; ks < 16; ks += 2) {
        bf16x8 a0 = *(const bf16x8*)(ar + kb + (ks << 5));
        bf16x8 b0 = *(const bf16x8*)(br + kb + (ks << 5));
        bf16x8 a1 = *(const bf16x8*)(ar + kb + ((ks + 1) << 5));
        bf16x8 b1 = *(const bf16x8*)(br + kb + ((ks + 1) << 5));
        acc0 = __builtin_amdgcn_mfma_f32_16x16x32_bf16(a0, b0, acc0, 0, 0, 0);
        acc1 = __builtin_amdgcn_mfma_f32_16x16x32_bf16(a1, b1, acc1, 0, 0, 0);
    }
#pragma unroll
    for (int r = 0; r < 4; ++r) {
        int m = m0 + ((l >> 4) << 2) + r;
        out[(size_t)m * 512 + ncol] = acc0[r] + acc1[r];
    }
}

extern "C" void kernel_launch(void* const* d_in, const int* in_sizes, int n_in,
                              void* d_out, int out_size, void* d_ws, size_t ws_size,
                              hipStream_t stream) {
    const float* x      = (const float*)d_in[0];
    const float* w_qkv  = (const float*)d_in[1];
    const float* w_out  = (const float*)d_in[2];
    const float* nullkv = (const float*)d_in[3];
    const float* ln_g   = (const float*)d_in[4];
    const float* ln_b   = (const float*)d_in[5];
    float* ws = (float*)d_ws;
    float* out = (float*)d_out;

    float* base = ws;
    __bf16* xnh = (__bf16*)(base);              base += 262144;   // 1024*512 bf16
    __bf16* xnl = (__bf16*)(base);              base += 262144;
    __bf16* wqh = (__bf16*)(base);              base += 393216;   // 1536*512 bf16
    __bf16* wql = (__bf16*)(base);              base += 393216;
    __bf16* qh  = (__bf16*)(base);              base += 262144;   // 8*1024*64
    __bf16* ql  = (__bf16*)(base);              base += 262144;
    __bf16* kh  = (__bf16*)(base);              base += 278528;   // 8*1088*64
    __bf16* kl  = (__bf16*)(base);              base += 278528;
    __bf16* vT  = (__bf16*)(base);              base += 270336;   // 8*64*1056
    __bf16* wo  = (__bf16*)(base);              base += 131072;   // 512*512
    __bf16* ao  = (__bf16*)(base);              base += 262144;   // 1024*512

    hipLaunchKernelGGL(prep_kernel, dim3(772),    dim3(256), 0, stream,
                       x, ln_g, ln_b, w_qkv, w_out, nullkv,
                       xnh, xnl, wqh, wql, wo, kh, kl, vT);
    hipLaunchKernelGGL(qkv_mfma,    dim3(32, 24), dim3(256), 0, stream, xnh, xnl, wqh, wql, qh, ql, kh, kl, vT);
    hipLaunchKernelGGL(qkcdpv_kernel, dim3(64, 8), dim3(512), 0, stream, qh, ql, kh, kl, vT, ao);
    hipLaunchKernelGGL(out_mfma,    dim3(64, 8),  dim3(256), 0, stream, ao, wo, out);
}